// Round 1
// 59.731 us; speedup vs baseline: 1.0151x; 1.0151x over previous
//
#include <hip/hip_runtime.h>
#include <math.h>

#define MASKN 64
#define NPTS 32
#define INV_STRIDE 0.0625f                   // 1/16, exact power of two
#define NEG_INV_TWO_SIGMA2 (-1.0f / 882.0f)  // -1 / (2*21*21)

// grid = 2*B blocks: blockIdx.x>>1 = batch, blockIdx.x&1 = row-half.
// 2 blocks/CU -> 2 waves/SIMD (was 1), hiding LDS/global latency.
__global__ __launch_bounds__(256, 2) void fused_masks_kernel(
    const float* __restrict__ boxes,      // (B,4)
    const float* __restrict__ pts,        // (B,32,2)
    float* __restrict__ out_bbox,         // (B,64,64)
    float* __restrict__ out_point)        // (B,64,64)
{
    const int b       = blockIdx.x >> 1;
    const int rowbase = (blockIdx.x & 1) * (MASKN / 2);   // 0 or 32
    const int t       = threadIdx.x;

    __shared__ float rf[NPTS][MASKN];   // valid ? exp(-(i-py)^2/882) : 0
    __shared__ float cf[NPTS][MASKN];   // valid ? exp(-(j-px)^2/882) : 0

    // Table fill: 8 iterations of 256 threads cover 32*64 entries of each
    // table. p = e>>6 is wave-uniform (wave64) -> pts loads are scalar,
    // px/py recomputed per wave inline (no shared staging, no extra sync).
    for (int e = t; e < NPTS * MASKN; e += 256) {
        const int p = e >> 6;          // wave-uniform
        const int i = e & 63;          // lane id
        const float x = pts[((size_t)b * NPTS + p) * 2 + 0];
        const float y = pts[((size_t)b * NPTS + p) * 2 + 1];
        const int px = (int)floorf(x * INV_STRIDE);
        const int py = (int)floorf(y * INV_STRIDE);
        const float v = (px >= 0 && py >= 0 && px < MASKN && py < MASKN) ? 1.0f : 0.0f;
        const float dy = (float)(i - py);
        const float dx = (float)(i - px);
        // invalid: v=0; exp underflows to 0 for huge |d| so no NaN
        rf[p][i] = v * __expf(dy * dy * NEG_INV_TWO_SIGMA2);
        cf[p][i] = v * __expf(dx * dx * NEG_INV_TWO_SIGMA2);
    }

    // Box bounds: wave-uniform global loads (L1-hit / scalar), computed by
    // every thread -- removes the t==0 prologue and its __syncthreads.
    const float x0 = boxes[b * 4 + 0], y0 = boxes[b * 4 + 1];
    const float x1 = boxes[b * 4 + 2], y1 = boxes[b * 4 + 3];
    const int xmin_i = max((int)floorf(fminf(x0, x1) * INV_STRIDE), 0);
    const int xmax_i = min((int)floorf(fmaxf(x0, x1) * INV_STRIDE) + 1, MASKN);
    const int ymin_i = max((int)floorf(fminf(y0, y1) * INV_STRIDE), 0);
    const int ymax_i = min((int)floorf(fmaxf(y0, y1) * INV_STRIDE) + 1, MASKN);

    __syncthreads();   // the ONLY barrier

    // 2 rows x 4 cols per thread: per point 1x ds_read_b128 + 1x ds_read_b64
    // (was 1x b128 + 4x b32).
    const int j0 = (t & 15) * 4;                  // column base
    const int r0 = rowbase + (t >> 4) * 2;        // rows r0, r0+1 (even -> b64 aligned)

    float4 m0 = make_float4(0.f, 0.f, 0.f, 0.f);
    float4 m1 = make_float4(0.f, 0.f, 0.f, 0.f);

    #pragma unroll 4
    for (int p = 0; p < NPTS; ++p) {
        const float4 c  = *(const float4*)&cf[p][j0];   // ds_read_b128, conflict-free
        const float2 ry = *(const float2*)&rf[p][r0];   // ds_read_b64, 16-lane broadcast
        m0.x = fmaxf(m0.x, ry.x * c.x);
        m0.y = fmaxf(m0.y, ry.x * c.y);
        m0.z = fmaxf(m0.z, ry.x * c.z);
        m0.w = fmaxf(m0.w, ry.x * c.w);
        m1.x = fmaxf(m1.x, ry.y * c.x);
        m1.y = fmaxf(m1.y, ry.y * c.y);
        m1.z = fmaxf(m1.z, ry.y * c.z);
        m1.w = fmaxf(m1.w, ry.y * c.w);
    }

    const size_t base = (size_t)b * (MASKN * MASKN);
    const float bx0 = (j0 + 0 >= xmin_i && j0 + 0 < xmax_i) ? 1.0f : 0.0f;
    const float bx1 = (j0 + 1 >= xmin_i && j0 + 1 < xmax_i) ? 1.0f : 0.0f;
    const float bx2 = (j0 + 2 >= xmin_i && j0 + 2 < xmax_i) ? 1.0f : 0.0f;
    const float bx3 = (j0 + 3 >= xmin_i && j0 + 3 < xmax_i) ? 1.0f : 0.0f;

    const int   idx0 = r0 * MASKN + j0;
    const float iny0 = (r0 + 0 >= ymin_i && r0 + 0 < ymax_i) ? 1.0f : 0.0f;
    const float iny1 = (r0 + 1 >= ymin_i && r0 + 1 < ymax_i) ? 1.0f : 0.0f;

    *(float4*)&out_point[base + idx0]         = m0;
    *(float4*)&out_point[base + idx0 + MASKN] = m1;
    *(float4*)&out_bbox[base + idx0]          = make_float4(iny0 * bx0, iny0 * bx1, iny0 * bx2, iny0 * bx3);
    *(float4*)&out_bbox[base + idx0 + MASKN]  = make_float4(iny1 * bx0, iny1 * bx1, iny1 * bx2, iny1 * bx3);
}

extern "C" void kernel_launch(void* const* d_in, const int* in_sizes, int n_in,
                              void* d_out, int out_size, void* d_ws, size_t ws_size,
                              hipStream_t stream) {
    const float* boxes = (const float*)d_in[0];
    const float* pts   = (const float*)d_in[1];
    float* out = (float*)d_out;

    const int B = in_sizes[0] / 4;                 // 256
    float* out_bbox  = out;                        // (B,64,64)
    float* out_point = out + (size_t)B * MASKN * MASKN;

    fused_masks_kernel<<<dim3(2 * B), dim3(256), 0, stream>>>(boxes, pts, out_bbox, out_point);
}